// Round 1
// baseline (6279.750 us; speedup 1.0000x reference)
//
#include <hip/hip_runtime.h>

// Problem constants
#define SEQ   512
#define BATCH 64
#define DIN   1024
#define DH    1024
#define NBLK  128   // one block per 8 hidden units
#define NGRP  16    // arrival groups (8 blocks each)
#define WPG   32    // wave arrivals per group per step (8 blocks * 4 waves)

typedef unsigned short u16;
typedef __attribute__((ext_vector_type(8))) short  short8;   // 8 x bf16 MFMA operand
typedef __attribute__((ext_vector_type(4))) float  floatx4;  // MFMA accumulator

static __device__ __forceinline__ u16 f2bf(float f) {
    union { float f; unsigned u; } v; v.f = f;
    unsigned r = v.u + 0x7fffu + ((v.u >> 16) & 1u);   // RNE
    return (u16)(r >> 16);
}

static __device__ __forceinline__ float sigmoid_f(float x) {
    return 1.0f / (1.0f + __expf(-x));
}

static __device__ __forceinline__ float tanh_f(float x) {
    x = fminf(10.0f, fmaxf(-10.0f, x));
    float e = __expf(2.0f * x);
    return (e - 1.0f) / (e + 1.0f);
}

// Build a bf16 A-fragment from 8 consecutive fp32 (on-the-fly cast).
static __device__ __forceinline__ short8 xfrag(const float* xr) {
    float4 a0 = *(const float4*)xr;
    float4 a1 = *(const float4*)(xr + 4);
    short8 ax;
    ax[0] = (short)f2bf(a0.x); ax[1] = (short)f2bf(a0.y);
    ax[2] = (short)f2bf(a0.z); ax[3] = (short)f2bf(a0.w);
    ax[4] = (short)f2bf(a1.x); ax[5] = (short)f2bf(a1.y);
    ax[6] = (short)f2bf(a1.z); ax[7] = (short)f2bf(a1.w);
    return ax;
}

#define MFMA16(a, b, c) __builtin_amdgcn_mfma_f32_16x16x32_bf16((a), (b), (c), 0, 0, 0)

// HIST=1: 512-deep h history (fresh addresses every step -> plain consumer
//         loads are always coherent), sc0sc1 write-through h stores, relaxed
//         group counters.
// HIST=0: fallback 2-deep buffer with release/acquire counter semantics
//         (L2 writeback + invalidate), correct with tiny workspace.
template <int HIST>
__global__ void __launch_bounds__(256, 1) lstm_persist(
    const float* __restrict__ X,
    const float* __restrict__ Wf, const float* __restrict__ Wi,
    const float* __restrict__ Wg, const float* __restrict__ Wo,
    const float* __restrict__ bfp, const float* __restrict__ bip,
    const float* __restrict__ bgp, const float* __restrict__ bop,
    float* __restrict__ out,        // outputs(SEQ,B,DH) ++ h_n(B,DH) ++ c_n(B,DH)
    u16*   __restrict__ hbuf,       // [t][b][DH] bf16
    unsigned* __restrict__ cnt)     // 16 group counters, 64 B apart, pre-zeroed
{
    // B-frags [kk][ct][lane][8]; ct = column-tile (0: gates f,i ; 1: gates g,o)
    __shared__ __align__(16) u16 Wx_l[32 * 2 * 64 * 8];   // 64 KiB
    __shared__ __align__(16) u16 Wh_l[32 * 2 * 64 * 8];   // 64 KiB
    __shared__ __align__(16) float G[4][16][34];          // per-wave gate transpose
    __shared__ unsigned pub;                              // wave0 -> waves1-3 ready mask

    const int tid = threadIdx.x;
    const int blk = blockIdx.x;
    const int j0  = blk * 8;

    if (tid == 0) pub = 0u;

    // One-time W fragment fill. Frag element (kk,ct,lane,j) = W[col][k]:
    // col c = ct*16 + (lane&15) -> gate=c>>3, jj=c&7 ; k = kk*32 + (lane>>4)*8 + j.
    for (int i = tid; i < 32 * 2 * 64 * 8; i += 256) {
        int j = i & 7, lane_f = (i >> 3) & 63, ct = (i >> 9) & 1, kk = i >> 10;
        int n = lane_f & 15, kqf = lane_f >> 4;
        int k = kk * 32 + kqf * 8 + j;
        int c = ct * 16 + n;
        int gate = c >> 3, jj = c & 7;
        const float* Wp = gate == 0 ? Wf : gate == 1 ? Wi : gate == 2 ? Wg : Wo;
        const float* row = Wp + (size_t)(j0 + jj) * (DIN + DH);
        Wx_l[i] = f2bf(row[k]);
        Wh_l[i] = f2bf(row[DIN + k]);
    }
    __syncthreads();   // the ONLY barrier in this kernel

    const int lane = tid & 63;
    const int w    = tid >> 6;          // wave id; wave w owns batch rows [16w,16w+16)
    const int kq   = lane >> 4;
    const int cc   = lane & 15;
    const int row_glob = w * 16 + cc;

    // bias folded into accumulator init (per output column, same for all 4 acc rows)
    const float bv0 = ((cc >> 3) ? bip : bfp)[j0 + (cc & 7)];
    const float bv1 = ((cc >> 3) ? bop : bgp)[j0 + (cc & 7)];
    const floatx4 binit0 = {bv0, bv0, bv0, bv0};
    const floatx4 binit1 = {bv1, bv1, bv1, bv1};

    const short8* WxF = (const short8*)Wx_l;
    const short8* WhF = (const short8*)Wh_l;
    unsigned* myCnt = cnt + (blk >> 3) * 16;
    volatile unsigned* pubv = &pub;

    // pointwise assignment: lane -> (batch row pr, hidden pair 2*jp)
    const int pr = lane >> 2, jp = lane & 3;
    float cs0 = 0.f, cs1 = 0.f;

    // Prologue: x-projection for t=0
    floatx4 x0 = binit0, x1 = binit1;
    {
        const float* xr = X + (size_t)row_glob * DIN + kq * 8;
        #pragma unroll 4
        for (int kk = 0; kk < 32; ++kk) {
            short8 ax = xfrag(xr + kk * 32);
            x0 = MFMA16(ax, WxF[(kk * 2 + 0) * 64 + lane], x0);
            x1 = MFMA16(ax, WxF[(kk * 2 + 1) * 64 + lane], x1);
        }
    }

    for (int t = 0; t < SEQ; ++t) {
        floatx4 A0 = x0, A1 = x1;

        // ---- recurrent chain: h(t-1) @ Wh, consumed as arrival groups land ----
        if (t > 0) {
            const u16* hb = hbuf + (size_t)(HIST ? (t - 1) : ((t - 1) & 1)) * (BATCH * DH)
                            + (size_t)row_glob * DH + kq * 8;
            const unsigned target = (unsigned)t * WPG;
            unsigned avail = 0u, lastPub = 0u;
            auto pollAvail = [&]() -> unsigned {
                unsigned av;
                if (w == 0) {
                    // one 16-lane gather = all 16 counters in a single LLC round trip
                    unsigned cv = target;
                    if (lane < NGRP)
                        cv = __hip_atomic_load(&cnt[lane * 16],
                                HIST ? __ATOMIC_RELAXED : __ATOMIC_ACQUIRE,
                                __HIP_MEMORY_SCOPE_AGENT);
                    av = (unsigned)__ballot(cv >= target) & 0xFFFFu;
                    if (av != lastPub) { *pubv = ((unsigned)t << 16) | av; lastPub = av; }
                } else {
                    // waves 1-3: LDS spin only, zero global poll traffic; monotone encoding
                    unsigned f = *pubv;
                    unsigned ft = f >> 16;
                    av = (ft > (unsigned)t) ? 0xFFFFu
                       : ((ft == (unsigned)t) ? (f & 0xFFFFu) : 0u);
                }
                return av;
            };
            // compiler fence after each wait: forbids hoisting h loads above the poll
            #define WAITG(g) \
                while (!((avail >> (g)) & 1u)) { \
                    avail = pollAvail(); \
                    if (!((avail >> (g)) & 1u)) __builtin_amdgcn_s_sleep(1); \
                } \
                asm volatile("" ::: "memory");
            #define LOADG(g) \
                short8 aA##g = *(const short8*)(hb + (2 * (g)) * 32); \
                short8 aB##g = *(const short8*)(hb + (2 * (g) + 1) * 32);
            #define MFMAG(g) \
                A0 = MFMA16(aA##g, WhF[(4 * (g) + 0) * 64 + lane], A0); \
                A1 = MFMA16(aA##g, WhF[(4 * (g) + 1) * 64 + lane], A1); \
                A0 = MFMA16(aB##g, WhF[(4 * (g) + 2) * 64 + lane], A0); \
                A1 = MFMA16(aB##g, WhF[(4 * (g) + 3) * 64 + lane], A1);
            // phase 1: issue all 32 h-fragment loads (named regs, full MLP)
            WAITG(0)  LOADG(0)  WAITG(1)  LOADG(1)  WAITG(2)  LOADG(2)  WAITG(3)  LOADG(3)
            WAITG(4)  LOADG(4)  WAITG(5)  LOADG(5)  WAITG(6)  LOADG(6)  WAITG(7)  LOADG(7)
            WAITG(8)  LOADG(8)  WAITG(9)  LOADG(9)  WAITG(10) LOADG(10) WAITG(11) LOADG(11)
            WAITG(12) LOADG(12) WAITG(13) LOADG(13) WAITG(14) LOADG(14) WAITG(15) LOADG(15)
            // phase 2: straight-line MFMA chain (loads already ~landed)
            MFMAG(0)  MFMAG(1)  MFMAG(2)  MFMAG(3)  MFMAG(4)  MFMAG(5)  MFMAG(6)  MFMAG(7)
            MFMAG(8)  MFMAG(9)  MFMAG(10) MFMAG(11) MFMAG(12) MFMAG(13) MFMAG(14) MFMAG(15)
            #undef WAITG
            #undef LOADG
            #undef MFMAG
        }

        // ---- per-wave pointwise: wave-private LDS transpose, NO barrier ----
        // C/D layout: col = lane&15, row = kq*4+q (batch within wave tile)
        #pragma unroll
        for (int q = 0; q < 4; ++q) {
            G[w][kq * 4 + q][cc]      = A0[q];
            G[w][kq * 4 + q][16 + cc] = A1[q];
        }
        asm volatile("s_waitcnt lgkmcnt(0)" ::: "memory");

        const float* Gr = &G[w][pr][0];
        float2 vF  = *(const float2*)(Gr + 2 * jp);
        float2 vI  = *(const float2*)(Gr + 8  + 2 * jp);
        float2 vGg = *(const float2*)(Gr + 16 + 2 * jp);
        float2 vO  = *(const float2*)(Gr + 24 + 2 * jp);
        float F0 = sigmoid_f(vF.x),  F1 = sigmoid_f(vF.y);
        float I0 = sigmoid_f(vI.x),  I1 = sigmoid_f(vI.y);
        float g0 = tanh_f(vGg.x),    g1 = tanh_f(vGg.y);
        float O0 = sigmoid_f(vO.x),  O1 = sigmoid_f(vO.y);
        cs0 = F0 * cs0 + I0 * g0;
        cs1 = F1 * cs1 + I1 * g1;
        float hv0 = O0 * tanh_f(cs0);
        float hv1 = O1 * tanh_f(cs1);
        const int b = w * 16 + pr;
        float2 ho; ho.x = hv0; ho.y = hv1;
        float* outp = out + (size_t)t * (BATCH * DH) + (size_t)b * DH + j0 + 2 * jp;

        if (t < SEQ - 1) {
            u16* dst = hbuf + (size_t)(HIST ? t : (t & 1)) * (BATCH * DH)
                       + (size_t)b * DH + j0 + 2 * jp;
            unsigned hv = (unsigned)f2bf(hv0) | ((unsigned)f2bf(hv1) << 16);
            if (HIST) {
                // h store first (write-through to LLC), out store second, then
                // vmcnt(1): wait only for the h store's LLC ack, leave out pending.
                asm volatile("global_store_dword %0, %1, off sc0 sc1"
                             :: "v"(dst), "v"(hv) : "memory");
                *(float2*)outp = ho;
                asm volatile("s_waitcnt vmcnt(1)" ::: "memory");
                if (lane == 0)
                    (void)__hip_atomic_fetch_add(myCnt, 1u, __ATOMIC_RELAXED,
                                                 __HIP_MEMORY_SCOPE_AGENT);
            } else {
                *(unsigned*)dst = hv;
                *(float2*)outp = ho;
                asm volatile("s_waitcnt vmcnt(0)" ::: "memory");
                if (lane == 0)
                    (void)__hip_atomic_fetch_add(myCnt, 1u, __ATOMIC_RELEASE,
                                                 __HIP_MEMORY_SCOPE_AGENT);
            }
            // x-projection for t+1 — overlaps other blocks' arrivals
            x0 = binit0; x1 = binit1;
            const float* xr = X + ((size_t)(t + 1) * BATCH + row_glob) * DIN + kq * 8;
            #pragma unroll 4
            for (int kk = 0; kk < 32; ++kk) {
                short8 ax = xfrag(xr + kk * 32);
                x0 = MFMA16(ax, WxF[(kk * 2 + 0) * 64 + lane], x0);
                x1 = MFMA16(ax, WxF[(kk * 2 + 1) * 64 + lane], x1);
            }
        } else {
            *(float2*)outp = ho;
            *(float2*)(out + (size_t)SEQ * (BATCH * DH) + (size_t)b * DH + j0 + 2 * jp) = ho;
            float2 co; co.x = cs0; co.y = cs1;
            *(float2*)(out + (size_t)SEQ * (BATCH * DH) + (BATCH * DH)
                       + (size_t)b * DH + j0 + 2 * jp) = co;
        }
    }
}

extern "C" void kernel_launch(void* const* d_in, const int* in_sizes, int n_in,
                              void* d_out, int out_size, void* d_ws, size_t ws_size,
                              hipStream_t stream) {
    (void)in_sizes; (void)n_in; (void)out_size;
    const float* X   = (const float*)d_in[0];
    const float* Wf  = (const float*)d_in[1];
    const float* bfv = (const float*)d_in[2];
    const float* Wi  = (const float*)d_in[3];
    const float* biv = (const float*)d_in[4];
    const float* Wg  = (const float*)d_in[5];
    const float* bgv = (const float*)d_in[6];
    const float* Wo  = (const float*)d_in[7];
    const float* bov = (const float*)d_in[8];
    float* out = (float*)d_out;

    unsigned char* ws = (unsigned char*)d_ws;
    unsigned* cnt = (unsigned*)ws;              // 16 counters, 64 B apart
    u16* hbuf     = (u16*)(ws + 4096);

    // zero counters (ws is re-poisoned to 0xAA before every timed launch)
    hipMemsetAsync(ws, 0, 4096, stream);

    const size_t need_hist = 4096 + (size_t)SEQ * BATCH * DH * 2;   // 64 MiB + 4 KiB
    if (ws_size >= need_hist) {
        lstm_persist<1><<<NBLK, 256, 0, stream>>>(
            X, Wf, Wi, Wg, Wo, bfv, biv, bgv, bov, out, hbuf, cnt);
    } else {
        lstm_persist<0><<<NBLK, 256, 0, stream>>>(
            X, Wf, Wi, Wg, Wo, bfv, biv, bgv, bov, out, hbuf, cnt);
    }
}